// Round 11
// baseline (324.706 us; speedup 1.0000x reference)
//
#include <hip/hip_runtime.h>
#include <hip/hip_bf16.h>

typedef unsigned short u16;
typedef unsigned int   u32;
typedef __attribute__((ext_vector_type(8))) short bf16x8;
typedef __attribute__((ext_vector_type(4))) short bf16x4;
typedef __attribute__((ext_vector_type(4))) float f32x4;
typedef __attribute__((ext_vector_type(4))) unsigned short u16x4;

__device__ __forceinline__ u16 f32_to_bf16bits(float f) {
    u32 x = __float_as_uint(f);
    u32 r = (x + 0x7fffu + ((x >> 16) & 1u)) >> 16;   // RNE
    return (u16)r;
}
__device__ __forceinline__ float bf16bits_to_f32(u16 u) {
    return __uint_as_float(((u32)u) << 16);
}
__device__ __forceinline__ u32 cvt_pk_bf16(float lo, float hi) {
    u32 r;
    asm("v_cvt_pk_bf16_f32 %0, %1, %2" : "=v"(r) : "v"(lo), "v"(hi));
    return r;
}

// async global->LDS, 16B per lane. LDS dest is wave-uniform base + lane*16.
__device__ __forceinline__ void async_copy16(void* lds, const void* g) {
    __builtin_amdgcn_global_load_lds(
        (__attribute__((address_space(1))) void*)(g),
        (__attribute__((address_space(3))) void*)(lds), 16, 0, 0);
}

#define VMCNT(n)  asm volatile("s_waitcnt vmcnt(" #n ")" ::: "memory")
#define LGKMC0()  asm volatile("s_waitcnt lgkmcnt(0)" ::: "memory")
#define ENDBAR()  __builtin_amdgcn_s_barrier()

// ---------------------------------------------------------------- convert x
__global__ void convert_f32_bf16(const float* __restrict__ src, u16* __restrict__ dst, int n4) {
    const int i = blockIdx.x * 256 + threadIdx.x;
    if (i >= n4) return;
    const float4 v = ((const float4*)src)[i];
    u16x4 o = { f32_to_bf16bits(v.x), f32_to_bf16bits(v.y),
                f32_to_bf16bits(v.z), f32_to_bf16bits(v.w) };
    ((u16x4*)dst)[i] = o;
}

// ------------------------------------------- weight transpose fp32(K,N)->bf16(N,K)
__global__ void transpose_wT(const float* __restrict__ src, u16* __restrict__ dst,
                             int N, int dstStride) {
    __shared__ float tile[32][129];
    const int n0 = blockIdx.x * 128, k0 = blockIdx.y * 32;
    const int tx = threadIdx.x, ty = threadIdx.y;      // (32, 8)
#pragma unroll
    for (int j = 0; j < 4; ++j)
#pragma unroll
        for (int i = 0; i < 4; ++i)
            tile[ty + 8*j][tx + 32*i] = src[(size_t)(k0 + ty + 8*j) * N + n0 + tx + 32*i];
    __syncthreads();
    const int tid = ty * 32 + tx;
    const int c = tid & 15, nl0 = tid >> 4;
#pragma unroll
    for (int s = 0; s < 8; ++s) {
        const int nl = nl0 + s * 16;
        const u32 pk = (u32)f32_to_bf16bits(tile[2*c][nl])
                     | ((u32)f32_to_bf16bits(tile[2*c + 1][nl]) << 16);
        *(u32*)&dst[(size_t)(n0 + nl) * dstStride + k0 + 2*c] = pk;
    }
}

// ------------------------------------------- V transpose bf16 (s,dcol)->(dcol,s)
__global__ void transpose_v(const u16* __restrict__ qkv, u16* __restrict__ vT) {
    __shared__ u16 tile[32][34];
    const int s0 = blockIdx.x * 32, n0 = blockIdx.y * 32;
    const int tx = threadIdx.x, ty = threadIdx.y;
#pragma unroll
    for (int i = 0; i < 4; ++i)
        tile[ty + i*8][tx] = qkv[(size_t)(s0 + ty + i*8) * 6144 + 5120 + n0 + tx];
    __syncthreads();
#pragma unroll
    for (int i = 0; i < 4; ++i)
        vT[(size_t)(n0 + ty + i*8) * 2048 + s0 + tx] = tile[tx][ty + i*8];
}

// ---------------------------------------------------------------- RoPE in place
__global__ void rope_kernel(u32* __restrict__ qkv, const float* __restrict__ cosp,
                            const float* __restrict__ sinp) {
    const int s = blockIdx.x;
    const int h = blockIdx.y * 4 + (threadIdx.x >> 6);
    const int p = threadIdx.x & 63;
    const size_t off = ((size_t)s * 6144 + h * 128) >> 1;
    const u32 packed = qkv[off + p];
    const float c  = cosp[s*64 + p], sn = sinp[s*64 + p];
    const float t1 = bf16bits_to_f32((u16)(packed & 0xffffu));
    const float t2 = bf16bits_to_f32((u16)(packed >> 16));
    const float o1 = t1 * c - t2 * sn;
    const float o2 = t1 * sn + t2 * c;
    qkv[off + p] = (u32)f32_to_bf16bits(o1) | ((u32)f32_to_bf16bits(o2) << 16);
}

// ---------------------------------------------------------------- big-phase GEMM
// C[M,N] = A[M,K] * B[N,K]^T.  BM=128, BN=NF*64 (384 qkv / 256 out), BK=64.
// Grid 16x16 = 256 blocks (full chip), 512 thr = 8 waves (2m x 4n);
// wave = 64r x NF*16c -> 4 x NF frags of 16x16x32, 8*NF MFMA/ktile.
// ONE compute phase per ktile: hoist all 4*2 + NF*2 ds_read_b128 into
// registers, then all MFMAs — the compiler inserts fine-grained counted
// lgkmcnt between reads and first uses, so reads stream under MFMA
// (no per-quadrant barrier/lgkmcnt(0) lockstep).  Per ktile only:
//   lgkmcnt(0); barrier;            // all waves done reading buf b
//   stage(t+2 -> buf b);            // SCALLS global_load_lds
//   vmcnt(SCALLS);                  // retire ktile t+1's stages (counted!)
//   barrier;                        // buf b^1 visible to all for iter t+1
// LDS: A[2buf][2half][64][128B] = 32KB @0; B[2buf][2half][BN/2][128B] @32768.
template<int NF, bool BF16OUT>
__global__ __launch_bounds__(512, 2) void gemm_big(
    const u16* __restrict__ A, const u16* __restrict__ B, void* __restrict__ Cv,
    const int N, const int K) {
    constexpr int BN     = NF * 64;
    constexpr int BHALF  = (BN / 2) * 128;       // B half-tile bytes
    constexpr int BCALLS = BHALF / 8192;         // stage calls per B half (3 or 2)
    __shared__ __align__(16) char sm[32768 + 4 * BHALF];

    const int tid = threadIdx.x;
    const int w = tid >> 6, l = tid & 63;
    const int wm = w >> 2, wn = w & 3, bh = wn >> 1;
    const int g = l >> 4, c0 = l & 15;
    const int bm = blockIdx.x >> 4, bn = blockIdx.x & 15;

    const int srow   = w*8 + (l >> 3);           // staging row within 64-row round
    const int schunk = (l & 7) ^ (l >> 3);       // pre-swizzled source chunk
    const u16* Abase = A + (size_t)(bm*128 + srow) * K + schunk*8;
    const u16* Bbase = B + (size_t)(bn*BN  + srow) * K + schunk*8;

    f32x4 acc[4][NF] = {};

    auto stage = [&](int kt, int b) {
#pragma unroll
        for (int h = 0; h < 2; ++h)
            async_copy16(sm + (b*2 + h)*8192 + (w*8)*128,
                         Abase + (size_t)h*64*K + kt*64);
#pragma unroll
        for (int h = 0; h < 2; ++h) {
            char* dst = sm + 32768 + (b*2 + h)*BHALF + (w*8)*128;
            const u16* src = Bbase + (size_t)h*(BN/2)*K + kt*64;
#pragma unroll
            for (int r = 0; r < BCALLS; ++r)
                async_copy16(dst + r*8192, src + (size_t)r*64*K);
        }
    };

    const int nkt = K >> 6;    // 64

    // prologue: ktile0 -> buf0, ktile1 -> buf1; retire ktile0, keep 1 in flight
    stage(0, 0);
    stage(1, 1);
    if constexpr (NF == 6) VMCNT(8); else VMCNT(6);
    ENDBAR();

    for (int t = 0; t < nkt; ++t) {
        const int b = t & 1;
        // ---- hoist all fragments of buf b into registers (dk0 group first) ----
        bf16x8 afr[4][2], bfr[NF][2];
#pragma unroll
        for (int dk = 0; dk < 2; ++dk) {
#pragma unroll
            for (int mi = 0; mi < 4; ++mi) {
                const char* ab = sm + (b*2 + wm)*8192 + (mi*16 + c0)*128;
                afr[mi][dk] = *(const bf16x8*)(ab + (((dk*4 + g) ^ (c0 & 7)) * 16));
            }
#pragma unroll
            for (int ni = 0; ni < NF; ++ni) {
                const char* bb = sm + 32768 + (b*2 + bh)*BHALF
                               + ((wn & 1)*(BN/4) + ni*16 + c0)*128;
                bfr[ni][dk] = *(const bf16x8*)(bb + (((dk*4 + g) ^ (c0 & 7)) * 16));
            }
        }
        // ---- all MFMAs; compiler pipelines reads under these ----
        __builtin_amdgcn_s_setprio(1);
#pragma unroll
        for (int dk = 0; dk < 2; ++dk)
#pragma unroll
            for (int mi = 0; mi < 4; ++mi)
#pragma unroll
                for (int ni = 0; ni < NF; ++ni)
                    acc[mi][ni] = __builtin_amdgcn_mfma_f32_16x16x32_bf16(
                        afr[mi][dk], bfr[ni][dk], acc[mi][ni], 0, 0, 0);
        __builtin_amdgcn_s_setprio(0);
        // ---- rotate staging ----
        LGKMC0();           // all my reads of buf b complete
        ENDBAR();           // ... for every wave
        if (t + 2 < nkt) {
            stage(t + 2, b);
            if constexpr (NF == 6) VMCNT(8); else VMCNT(6);  // retire ktile t+1
        } else {
            VMCNT(0);       // tail: nothing new issued; drain ktile t+1
        }
        ENDBAR();           // buf b^1 ready for iter t+1
    }

#pragma unroll
    for (int m = 0; m < 4; ++m)
#pragma unroll
        for (int n = 0; n < NF; ++n) {
            const int row = bm*128 + wm*64 + m*16 + g*4;
            const int col = bn*BN + wn*(BN/4) + n*16 + c0;
#pragma unroll
            for (int r = 0; r < 4; ++r) {
                if (BF16OUT)
                    ((u16*)Cv)[(size_t)(row + r) * N + col] = f32_to_bf16bits(acc[m][n][r]);
                else
                    ((float*)Cv)[(size_t)(row + r) * N + col] = acc[m][n][r];
            }
        }
}

// ---------------------------------------------------------------- flash attention
// (unchanged — validated rounds 2-10)
__global__ __launch_bounds__(256, 2) void attn_kernel(
    const u16* __restrict__ qkv, const u16* __restrict__ vT, u16* __restrict__ outp) {
    __shared__ __align__(16) char lds[65536];
    const int tid = threadIdx.x;
    const int w = tid >> 6, l = tid & 63;
    const int g = l >> 4, c0 = l & 15;
    const int qt = (blockIdx.y < 16) ? blockIdx.x : (15 - (int)blockIdx.x);
    const int h = blockIdx.y;
    const int kvh = h >> 2;
    const int q0g = qt * 128;
    const int qrow0 = q0g + w * 32;

    const int srK = w*4 + g,        scK = c0 ^ srK;
    const int srV = w*8 + (l >> 3), scV = (l & 7) ^ (l >> 3);

#pragma unroll
    for (int i = 0; i < 8; ++i)
        async_copy16(lds + (i*16 + w*4) * 256,
                     qkv + (size_t)(q0g + i*16 + srK) * 6144 + h*128 + scK*8);
    __syncthreads();

#pragma unroll
    for (int i = 0; i < 4; ++i)
        async_copy16(lds + 32768 + (i*16 + w*4) * 256,
                     qkv + (size_t)(i*16 + srK) * 6144 + 4096 + kvh*128 + scK*8);
#pragma unroll
    for (int i = 0; i < 4; ++i)
        async_copy16(lds + 49152 + (i*32 + w*8) * 128,
                     vT + (size_t)(kvh*128 + i*32 + srV) * 2048 + scV*8);

    bf16x8 qf[2][4];
#pragma unroll
    for (int i = 0; i < 2; ++i)
#pragma unroll
        for (int dks = 0; dks < 4; ++dks) {
            const int row = w*32 + i*16 + c0;
            qf[i][dks] = *(const bf16x8*)(lds + row*256 + (((dks*4 + g) ^ c0) * 16));
        }
    __syncthreads();

    f32x4 o[2][8] = {};
    float lsum[2] = {0.f, 0.f};
    const int ntiles = 2*qt + 2;
    const float SC2 = 0.08838834764831845f * 1.4426950408889634f;

    for (int kt = 0; kt < ntiles; ++kt) {
        const int cur = kt & 1;
        const char* kb = lds + (cur ? 0 : 32768);
        const char* vb = lds + (cur ? 16384 : 49152);
        if (kt + 1 < ntiles) {
            char* kbn = lds + ((cur ^ 1) ? 0 : 32768);
            char* vbn = lds + ((cur ^ 1) ? 16384 : 49152);
#pragma unroll
            for (int i = 0; i < 4; ++i)
                async_copy16(kbn + (i*16 + w*4) * 256,
                             qkv + (size_t)((kt+1)*64 + i*16 + srK) * 6144 + 4096 + kvh*128 + scK*8);
#pragma unroll
            for (int i = 0; i < 4; ++i)
                async_copy16(vbn + (i*32 + w*8) * 128,
                             vT + (size_t)(kvh*128 + i*32 + srV) * 2048 + (kt+1)*64 + scV*8);
        }

        if (kt*64 <= qrow0 + 31) {
            f32x4 st[2][4] = {};
            __builtin_amdgcn_s_setprio(1);
#pragma unroll
            for (int dks = 0; dks < 4; ++dks) {
                bf16x8 kf[4];
#pragma unroll
                for (int j = 0; j < 4; ++j) {
                    const int row = j*16 + c0;
                    kf[j] = *(const bf16x8*)(kb + row*256 + (((dks*4 + g) ^ c0) * 16));
                }
#pragma unroll
                for (int i = 0; i < 2; ++i)
#pragma unroll
                    for (int j = 0; j < 4; ++j)
                        st[i][j] = __builtin_amdgcn_mfma_f32_16x16x32_bf16(
                            kf[j], qf[i][dks], st[i][j], 0, 0, 0);
            }
            __builtin_amdgcn_s_setprio(0);

            const bool diag = (kt*64 + 63) > qrow0;
            u32 pk[2][4][2];
#pragma unroll
            for (int i = 0; i < 2; ++i) {
                float rowsum = 0.f;
#pragma unroll
                for (int j = 0; j < 4; ++j) {
#pragma unroll
                    for (int r = 0; r < 4; ++r) {
                        float p = exp2f(st[i][j][r] * SC2);
                        if (diag) {
                            const int kgl = kt*64 + j*16 + g*4 + r;
                            const int qgl = qrow0 + i*16 + c0;
                            if (kgl > qgl) p = 0.f;
                        }
                        st[i][j][r] = p;
                        rowsum += p;
                    }
                    pk[i][j][0] = cvt_pk_bf16(st[i][j][0], st[i][j][1]);
                    pk[i][j][1] = cvt_pk_bf16(st[i][j][2], st[i][j][3]);
                }
                rowsum += __shfl_xor(rowsum, 16);
                rowsum += __shfl_xor(rowsum, 32);
                lsum[i] += rowsum;
            }

#pragma unroll
            for (int dks = 0; dks < 2; ++dks) {
                bf16x8 pf[2];
#pragma unroll
                for (int i = 0; i < 2; ++i) {
                    union { u32 u[4]; bf16x8 v; } pu;
                    pu.u[0] = pk[i][2*dks][0];   pu.u[1] = pk[i][2*dks][1];
                    pu.u[2] = pk[i][2*dks+1][0]; pu.u[3] = pk[i][2*dks+1][1];
                    pf[i] = pu.v;
                }
                __builtin_amdgcn_s_setprio(1);
#pragma unroll
                for (int dj = 0; dj < 8; ++dj) {
                    const int row = dj*16 + c0;
                    const int cg0 = (4*dks + (g >> 1)) ^ (row & 7);
                    const int cg1 = (4*dks + (g >> 1) + 2) ^ (row & 7);
                    union { struct { bf16x4 lo, hi; } p; bf16x8 v; } vu;
                    vu.p.lo = *(const bf16x4*)(vb + row*128 + cg0*16 + 8*(g & 1));
                    vu.p.hi = *(const bf16x4*)(vb + row*128 + cg1*16 + 8*(g & 1));
#pragma unroll
                    for (int i = 0; i < 2; ++i)
                        o[i][dj] = __builtin_amdgcn_mfma_f32_16x16x32_bf16(
                            vu.v, pf[i], o[i][dj], 0, 0, 0);
                }
                __builtin_amdgcn_s_setprio(0);
            }
        }
        __syncthreads();
    }

#pragma unroll
    for (int i = 0; i < 2; ++i) {
        const float rcp = 1.0f / lsum[i];
        const int qg = qrow0 + i*16 + c0;
#pragma unroll
        for (int dj = 0; dj < 8; ++dj) {
            u16x4 ov = { f32_to_bf16bits(o[i][dj][0] * rcp),
                         f32_to_bf16bits(o[i][dj][1] * rcp),
                         f32_to_bf16bits(o[i][dj][2] * rcp),
                         f32_to_bf16bits(o[i][dj][3] * rcp) };
            *(u16x4*)(outp + (size_t)qg * 4096 + h*128 + dj*16 + g*4) = ov;
        }
    }
}

// ---------------------------------------------------------------- launcher
extern "C" void kernel_launch(void* const* d_in, const int* in_sizes, int n_in,
                              void* d_out, int out_size, void* d_ws, size_t ws_size,
                              hipStream_t stream) {
    const float* x    = (const float*)d_in[0];
    const float* wq   = (const float*)d_in[1];
    const float* wk   = (const float*)d_in[2];
    const float* wv   = (const float*)d_in[3];
    const float* wo   = (const float*)d_in[4];
    const float* cosp = (const float*)d_in[5];
    const float* sinp = (const float*)d_in[6];
    // d_in[7] = mask — causality applied analytically in attn_kernel.

    char* ws = (char*)d_ws;
    u16* xb    = (u16*)(ws);                       //  16.8 MB  x bf16 (2048x4096)
    u16* wqkvT = (u16*)(ws + 16777216);            //  50.3 MB  [wq|wk|wv]^T (6144x4096)
    u16* woT   = (u16*)(ws + 67108864);            //  33.6 MB  wo^T (4096x4096)
    u16* qkv   = (u16*)(ws + 100663296);           //  25.2 MB  qkv (2048x6144)
    u16* vTb   = (u16*)(ws + 125829120);           //   4.2 MB  v^T (1024x2048)
    u16* attn  = (u16*)(ws + 130023424);           //  16.8 MB  attn out (2048x4096)

    dim3 tb(32, 8);
    convert_f32_bf16<<<8192, 256, 0, stream>>>(x, xb, 2097152);
    transpose_wT<<<dim3(32, 128), tb, 0, stream>>>(wq, wqkvT, 4096, 4096);
    transpose_wT<<<dim3(8, 128),  tb, 0, stream>>>(wk, wqkvT + (size_t)4096*4096, 1024, 4096);
    transpose_wT<<<dim3(8, 128),  tb, 0, stream>>>(wv, wqkvT + (size_t)5120*4096, 1024, 4096);
    transpose_wT<<<dim3(32, 128), tb, 0, stream>>>(wo, woT, 4096, 4096);

    gemm_big<6, true><<<256, 512, 0, stream>>>(xb, wqkvT, qkv, 6144, 4096);
    rope_kernel<<<dim3(2048, 10), 256, 0, stream>>>((u32*)qkv, cosp, sinp);
    transpose_v<<<dim3(64, 32), tb, 0, stream>>>(qkv, vTb);
    attn_kernel<<<dim3(16, 32), 256, 0, stream>>>(qkv, vTb, attn);
    gemm_big<4, false><<<256, 512, 0, stream>>>(attn, woT, d_out, 4096, 4096);
}